// Round 9
// baseline (898.001 us; speedup 1.0000x reference)
//
#include <hip/hip_runtime.h>
#include <hip/hip_cooperative_groups.h>

namespace cg = cooperative_groups;

constexpr int Uc = 100000;
constexpr int Ic = 50000;
constexpr int Nc = 150000;   // U + I
constexpr int Ec = 1000000;
constexpr int Bc = 16384;
constexpr int NBS = (Nc + 1023) / 1024;  // scan chunks = 147

typedef _Float16 h16;
union H8 { uint4 u; h16 h[8]; };

struct Args {
    const float *Gu, *Gi, *F, *pw, *pb, *ef;
    const int *un, *in_, *users, *items;
    float* out;
    float* Fp;
    float* dinv;
    unsigned* deg;
    int* rowptr;
    int* cursor;
    int* bsums;
    int2* csr;
    h16* xin;
    h16* xa;
    h16* xb;
};

// gather propagation phase: xn[n] = sum_e coef * x[src], fp16 rows, 8 lanes/row
__device__ __forceinline__ void gprop_phase(const int* __restrict__ rowptr,
                                            const int2* __restrict__ csr,
                                            const uint4* __restrict__ x,
                                            uint4* __restrict__ xn,
                                            int gtid, int nthr) {
    for (int t = gtid; t < Nc * 8; t += nthr) {
        int n = t >> 3, l = t & 7;
        int e0 = rowptr[n], e1 = rowptr[n + 1];
        float acc[8] = {0.f, 0.f, 0.f, 0.f, 0.f, 0.f, 0.f, 0.f};
        int e = e0;
        for (; e + 4 <= e1; e += 4) {
            int2 s0 = csr[e], s1 = csr[e + 1], s2 = csr[e + 2], s3 = csr[e + 3];
            H8 v0, v1, v2, v3;
            v0.u = x[s0.x * 8 + l];
            v1.u = x[s1.x * 8 + l];
            v2.u = x[s2.x * 8 + l];
            v3.u = x[s3.x * 8 + l];
            float c0 = __int_as_float(s0.y), c1 = __int_as_float(s1.y);
            float c2 = __int_as_float(s2.y), c3 = __int_as_float(s3.y);
#pragma unroll
            for (int j = 0; j < 8; ++j)
                acc[j] += c0 * (float)v0.h[j] + c1 * (float)v1.h[j]
                        + c2 * (float)v2.h[j] + c3 * (float)v3.h[j];
        }
        for (; e < e1; ++e) {
            int2 sc = csr[e];
            float c = __int_as_float(sc.y);
            H8 v; v.u = x[sc.x * 8 + l];
#pragma unroll
            for (int j = 0; j < 8; ++j) acc[j] += c * (float)v.h[j];
        }
        H8 o;
#pragma unroll
        for (int j = 0; j < 8; ++j) o.h[j] = (h16)acc[j];
        xn[n * 8 + l] = o.u;
    }
}

__global__ __launch_bounds__(256, 4) void mega(Args a) {
    cg::grid_group grid = cg::this_grid();
    const int tid = threadIdx.x;
    const int gtid = blockIdx.x * 256 + tid;
    const int nthr = gridDim.x * 256;
    __shared__ int sh[256];

    // ---- P0: zero deg ----
    for (int i = gtid; i < Nc; i += nthr) a.deg[i] = 0u;
    grid.sync();

    // ---- P1: fproj (block 0) + degree atomics ----
    if (blockIdx.x == 0 && tid < 64) {
        float s = 0.f;
#pragma unroll
        for (int j = 0; j < 64; ++j) s += a.F[tid * 64 + j] * a.pw[j];
        a.Fp[tid] = s;
    }
    for (int e = gtid; e < Ec; e += nthr) {
        atomicAdd(&a.deg[a.un[e]], 1u);
        atomicAdd(&a.deg[a.in_[e]], 1u);
    }
    grid.sync();

    // ---- P2: per-1024-chunk exclusive scan of deg -> rowptr, bsums; dinv ----
    for (int chunk = blockIdx.x; chunk < NBS; chunk += gridDim.x) {
        int base = chunk * 1024 + tid * 4;
        int v0 = (base + 0 < Nc) ? (int)a.deg[base + 0] : 0;
        int v1 = (base + 1 < Nc) ? (int)a.deg[base + 1] : 0;
        int v2 = (base + 2 < Nc) ? (int)a.deg[base + 2] : 0;
        int v3 = (base + 3 < Nc) ? (int)a.deg[base + 3] : 0;
        if (base + 0 < Nc) a.dinv[base + 0] = v0 ? rsqrtf((float)v0) : 0.f;
        if (base + 1 < Nc) a.dinv[base + 1] = v1 ? rsqrtf((float)v1) : 0.f;
        if (base + 2 < Nc) a.dinv[base + 2] = v2 ? rsqrtf((float)v2) : 0.f;
        if (base + 3 < Nc) a.dinv[base + 3] = v3 ? rsqrtf((float)v3) : 0.f;
        int s = v0 + v1 + v2 + v3;
        sh[tid] = s;
        __syncthreads();
        for (int off = 1; off < 256; off <<= 1) {
            int t = (tid >= off) ? sh[tid - off] : 0;
            __syncthreads();
            sh[tid] += t;
            __syncthreads();
        }
        int excl = sh[tid] - s;
        if (tid == 255) a.bsums[chunk] = sh[255];
        if (base + 0 < Nc) a.rowptr[base + 0] = excl;
        if (base + 1 < Nc) a.rowptr[base + 1] = excl + v0;
        if (base + 2 < Nc) a.rowptr[base + 2] = excl + v0 + v1;
        if (base + 3 < Nc) a.rowptr[base + 3] = excl + v0 + v1 + v2;
        __syncthreads();
    }
    grid.sync();

    // ---- P3: every block scans bsums in LDS; fix up rowptr, init cursor ----
    {
        int v = (tid < NBS) ? a.bsums[tid] : 0;
        sh[tid] = v;
        __syncthreads();
        for (int off = 1; off < 256; off <<= 1) {
            int t = (tid >= off) ? sh[tid - off] : 0;
            __syncthreads();
            sh[tid] += t;
            __syncthreads();
        }
        int excl = sh[tid] - v;
        __syncthreads();
        sh[tid] = excl;
        __syncthreads();
        for (int i = gtid; i < Nc; i += nthr) {
            int r = a.rowptr[i] + sh[i >> 10];
            a.rowptr[i] = r;
            a.cursor[i] = r;
        }
        if (gtid == 0) a.rowptr[Nc] = 2 * Ec;
    }
    grid.sync();

    // ---- P4: build CSR (ew projection fused) + xin fp16 convert ----
    {
        const float4* Fp4 = reinterpret_cast<const float4*>(a.Fp);
        const float pbv = a.pb[0];
        for (int t = gtid; t < Ec * 16; t += nthr) {
            int e = t >> 4, l = t & 15;
            float4 f = reinterpret_cast<const float4*>(a.ef)[(size_t)e * 16 + l];
            float4 w = Fp4[l];
            float s = f.x * w.x + f.y * w.y + f.z * w.z + f.w * w.w;
            s += __shfl_xor(s, 8, 16);
            s += __shfl_xor(s, 4, 16);
            s += __shfl_xor(s, 2, 16);
            s += __shfl_xor(s, 1, 16);
            if (l == 0 || l == 8) {
                int uu = a.un[e], ii = a.in_[e];
                float c = a.dinv[uu] * a.dinv[ii] * (s + pbv);
                if (l == 0) {
                    int pos = atomicAdd(&a.cursor[ii], 1);
                    a.csr[pos] = make_int2(uu, __float_as_int(c));
                } else {
                    int pos = atomicAdd(&a.cursor[uu], 1);
                    a.csr[pos] = make_int2(ii, __float_as_int(c));
                }
            }
        }
        uint4* xin4 = reinterpret_cast<uint4*>(a.xin);
        for (int t = gtid; t < Nc * 8; t += nthr) {
            const float4* g;
            int idx;
            if (t < Uc * 8) { g = reinterpret_cast<const float4*>(a.Gu); idx = t * 2; }
            else            { g = reinterpret_cast<const float4*>(a.Gi); idx = (t - Uc * 8) * 2; }
            float4 va = g[idx], vb = g[idx + 1];
            H8 o;
            o.h[0] = (h16)va.x; o.h[1] = (h16)va.y; o.h[2] = (h16)va.z; o.h[3] = (h16)va.w;
            o.h[4] = (h16)vb.x; o.h[5] = (h16)vb.y; o.h[6] = (h16)vb.z; o.h[7] = (h16)vb.w;
            xin4[t] = o.u;
        }
    }
    grid.sync();

    // ---- P5: layer 1 gprop xin -> xa ----
    gprop_phase(a.rowptr, a.csr, reinterpret_cast<const uint4*>(a.xin),
                reinterpret_cast<uint4*>(a.xa), gtid, nthr);
    grid.sync();

    // ---- P6: layer 2 gprop xa -> xb ----
    gprop_phase(a.rowptr, a.csr, reinterpret_cast<const uint4*>(a.xa),
                reinterpret_cast<uint4*>(a.xb), gtid, nthr);
    grid.sync();

    // ---- P7: fused batch accumulation + layer-3 + dot ----
    {
        const uint4* x1 = reinterpret_cast<const uint4*>(a.xa);
        const uint4* x2 = reinterpret_cast<const uint4*>(a.xb);
        for (int t = gtid; t < Bc * 8; t += nthr) {
            int wid = t >> 3, j8 = t & 7;
            int un = a.users[wid];
            int in_ = Uc + a.items[wid];
            float a2[2][8];
#pragma unroll
            for (int side = 0; side < 2; ++side) {
                int n = side ? in_ : un;
                const float4* g = side ? reinterpret_cast<const float4*>(a.Gi)
                                       : reinterpret_cast<const float4*>(a.Gu);
                int gi = (side ? (n - Uc) : n) * 16 + 2 * j8;
                float4 ba = g[gi], bb = g[gi + 1];
                H8 h1, h2;
                h1.u = x1[(size_t)n * 8 + j8];
                h2.u = x2[(size_t)n * 8 + j8];
                float acc[8];
                acc[0] = ba.x; acc[1] = ba.y; acc[2] = ba.z; acc[3] = ba.w;
                acc[4] = bb.x; acc[5] = bb.y; acc[6] = bb.z; acc[7] = bb.w;
#pragma unroll
                for (int j = 0; j < 8; ++j)
                    acc[j] += 0.5f * (float)h1.h[j] + (1.f / 3.f) * (float)h2.h[j];

                float su[8] = {0.f, 0.f, 0.f, 0.f, 0.f, 0.f, 0.f, 0.f};
                int e0 = a.rowptr[n], e1 = a.rowptr[n + 1];
                int e = e0;
                for (; e + 4 <= e1; e += 4) {
                    int2 s0 = a.csr[e], s1 = a.csr[e + 1], s2 = a.csr[e + 2], s3 = a.csr[e + 3];
                    H8 v0, v1, v2, v3;
                    v0.u = x2[(size_t)s0.x * 8 + j8];
                    v1.u = x2[(size_t)s1.x * 8 + j8];
                    v2.u = x2[(size_t)s2.x * 8 + j8];
                    v3.u = x2[(size_t)s3.x * 8 + j8];
                    float c0 = __int_as_float(s0.y), c1 = __int_as_float(s1.y);
                    float c2 = __int_as_float(s2.y), c3 = __int_as_float(s3.y);
#pragma unroll
                    for (int j = 0; j < 8; ++j)
                        su[j] += c0 * (float)v0.h[j] + c1 * (float)v1.h[j]
                               + c2 * (float)v2.h[j] + c3 * (float)v3.h[j];
                }
                for (; e < e1; ++e) {
                    int2 sc = a.csr[e];
                    float c = __int_as_float(sc.y);
                    H8 v; v.u = x2[(size_t)sc.x * 8 + j8];
#pragma unroll
                    for (int j = 0; j < 8; ++j) su[j] += c * (float)v.h[j];
                }
#pragma unroll
                for (int j = 0; j < 8; ++j) a2[side][j] = acc[j] + 0.25f * su[j];
            }
            float p = 0.f;
#pragma unroll
            for (int j = 0; j < 8; ++j) p += a2[0][j] * a2[1][j];
            p += __shfl_xor(p, 4, 8);
            p += __shfl_xor(p, 2, 8);
            p += __shfl_xor(p, 1, 8);
            if (j8 == 0) a.out[wid] = p;
        }
    }
}

// ---------------- launch ----------------

extern "C" void kernel_launch(void* const* d_in, const int* in_sizes, int n_in,
                              void* d_out, int out_size, void* d_ws, size_t ws_size,
                              hipStream_t stream) {
    Args a;
    a.Gu = (const float*)d_in[0];
    a.Gi = (const float*)d_in[1];
    a.F  = (const float*)d_in[2];
    a.pw = (const float*)d_in[3];
    a.pb = (const float*)d_in[4];
    a.ef = (const float*)d_in[5];
    const int* ei = (const int*)d_in[6];   // [2, 2E]
    a.users = (const int*)d_in[7];
    a.items = (const int*)d_in[8];
    a.out = (float*)d_out;

    float* ws = (float*)d_ws;
    a.Fp     = ws;                          // 64
    a.dinv   = a.Fp + 64;                   // N
    a.deg    = (unsigned*)(a.dinv + Nc);    // N
    a.rowptr = (int*)(a.deg + Nc);          // N+16
    a.cursor = a.rowptr + (Nc + 16);        // N
    a.bsums  = a.cursor + Nc;               // 256
    a.csr    = (int2*)(a.bsums + 256);      // 2E int2 (16 MB)
    a.xin    = (h16*)(a.csr + 2 * Ec);      // N*64 fp16
    a.xa     = a.xin + (size_t)Nc * 64;     // N*64 fp16
    a.xb     = a.xa + (size_t)Nc * 64;      // N*64 fp16

    a.un  = ei;            // user ids (first half of row 0)
    a.in_ = ei + 2 * Ec;   // item node ids >= U (first half of row 1)

    int maxPerCU = 0;
    hipOccupancyMaxActiveBlocksPerMultiprocessor(&maxPerCU, mega, 256, 0);
    if (maxPerCU < 1) maxPerCU = 1;
    int grid = 256 * maxPerCU;   // 256 CUs on MI355X
    if (grid > 1024) grid = 1024;

    void* params[] = {&a};
    hipLaunchCooperativeKernel((void*)mega, dim3(grid), dim3(256), params, 0, stream);
}

// Round 10
// 438.858 us; speedup vs baseline: 2.0462x; 2.0462x over previous
//
#include <hip/hip_runtime.h>

constexpr int Uc = 100000;
constexpr int Ic = 50000;
constexpr int Nc = 150000;   // U + I
constexpr int Ec = 1000000;
constexpr int Bc = 16384;
constexpr int NBS = (Nc + 1023) / 1024;  // scan chunks = 147

typedef _Float16 h16;
union H4 { uint2 u; h16 h[4]; };

// x layout: quarter-major fp16, xq[q][n][16] ; uint2 granule = 4 fp16
// addr in uint2 units: (q*Nc + n)*4 + l4, l4 in 0..3

// ---------------- kernels ----------------

__global__ void k_zero(uint4* __restrict__ deg4) {
    int i = blockIdx.x * blockDim.x + threadIdx.x;
    if (i < Nc / 4) deg4[i] = make_uint4(0u, 0u, 0u, 0u);
}

// deg count over undirected edges + (block 0) Fp[d] = F[d,:] @ pw
__global__ void k_deg2_fproj(const int* __restrict__ un, const int* __restrict__ in_,
                             unsigned* __restrict__ deg,
                             const float* __restrict__ F, const float* __restrict__ pw,
                             float* __restrict__ Fp) {
    if (blockIdx.x == 0 && threadIdx.x < 64) {
        int d = threadIdx.x;
        float s = 0.f;
#pragma unroll
        for (int j = 0; j < 64; ++j) s += F[d * 64 + j] * pw[j];
        Fp[d] = s;
    }
    int e = blockIdx.x * blockDim.x + threadIdx.x;
    if (e < Ec) {
        atomicAdd(&deg[un[e]], 1u);
        atomicAdd(&deg[in_[e]], 1u);
    }
}

// --- scan phase 1: per-1024-chunk exclusive scan of deg; also writes dinv ---
__global__ void k_scan1(const unsigned* __restrict__ deg, int* __restrict__ rowptr,
                        int* __restrict__ bsums, float* __restrict__ dinv) {
    __shared__ int sh[256];
    int tid = threadIdx.x, bid = blockIdx.x;
    int base = bid * 1024 + tid * 4;
    int v0 = (base + 0 < Nc) ? (int)deg[base + 0] : 0;
    int v1 = (base + 1 < Nc) ? (int)deg[base + 1] : 0;
    int v2 = (base + 2 < Nc) ? (int)deg[base + 2] : 0;
    int v3 = (base + 3 < Nc) ? (int)deg[base + 3] : 0;
    if (base + 0 < Nc) dinv[base + 0] = v0 ? rsqrtf((float)v0) : 0.f;
    if (base + 1 < Nc) dinv[base + 1] = v1 ? rsqrtf((float)v1) : 0.f;
    if (base + 2 < Nc) dinv[base + 2] = v2 ? rsqrtf((float)v2) : 0.f;
    if (base + 3 < Nc) dinv[base + 3] = v3 ? rsqrtf((float)v3) : 0.f;
    int s = v0 + v1 + v2 + v3;
    sh[tid] = s;
    __syncthreads();
    for (int off = 1; off < 256; off <<= 1) {
        int t = (tid >= off) ? sh[tid - off] : 0;
        __syncthreads();
        sh[tid] += t;
        __syncthreads();
    }
    int excl = sh[tid] - s;
    if (tid == 255) bsums[bid] = sh[255];
    if (base + 0 < Nc) rowptr[base + 0] = excl;
    if (base + 1 < Nc) rowptr[base + 1] = excl + v0;
    if (base + 2 < Nc) rowptr[base + 2] = excl + v0 + v1;
    if (base + 3 < Nc) rowptr[base + 3] = excl + v0 + v1 + v2;
}

// bsums scan folded in (each block redundantly scans the 147 sums in LDS)
__global__ void k_scan3(int* __restrict__ rowptr, const int* __restrict__ bsums,
                        int* __restrict__ cursor) {
    __shared__ int sh[256];
    int tid = threadIdx.x;
    int v = (tid < NBS) ? bsums[tid] : 0;
    sh[tid] = v;
    __syncthreads();
    for (int off = 1; off < 256; off <<= 1) {
        int t = (tid >= off) ? sh[tid - off] : 0;
        __syncthreads();
        sh[tid] += t;
        __syncthreads();
    }
    int excl = sh[tid] - v;
    __syncthreads();
    sh[tid] = excl;
    __syncthreads();
    int i = blockIdx.x * blockDim.x + threadIdx.x;
    if (i < Nc) {
        int r = rowptr[i] + sh[i >> 10];
        rowptr[i] = r;
        cursor[i] = r;
    }
    if (i == 0) rowptr[Nc] = 2 * Ec;
}

// fused: edge-weight projection + CSR scatter (both directions, same coef)
__global__ void k_build(const int* __restrict__ un, const int* __restrict__ in_,
                        const float* __restrict__ ef, const float* __restrict__ Fp,
                        const float* __restrict__ pb, const float* __restrict__ dinv,
                        int* __restrict__ cursor, int2* __restrict__ csr) {
    int t = blockIdx.x * blockDim.x + threadIdx.x;
    int e = t >> 4, l = t & 15;
    if (e >= Ec) return;
    float4 f = reinterpret_cast<const float4*>(ef)[(size_t)e * 16 + l];
    float4 w = reinterpret_cast<const float4*>(Fp)[l];
    float s = f.x * w.x + f.y * w.y + f.z * w.z + f.w * w.w;
    s += __shfl_xor(s, 8, 16);
    s += __shfl_xor(s, 4, 16);
    s += __shfl_xor(s, 2, 16);
    s += __shfl_xor(s, 1, 16);
    if (l == 0 || l == 8) {
        int uu = un[e], ii = in_[e];
        float c = dinv[uu] * dinv[ii] * (s + pb[0]);
        if (l == 0) {
            int pos = atomicAdd(&cursor[ii], 1);
            csr[pos] = make_int2(uu, __float_as_int(c));
        } else {
            int pos = atomicAdd(&cursor[uu], 1);
            csr[pos] = make_int2(ii, __float_as_int(c));
        }
    }
}

// convert concat(Gu,Gi) f32 -> xin fp16, quarter-major layout (write-coalesced)
__global__ void k_xin(const float* __restrict__ Gu, const float* __restrict__ Gi,
                      uint2* __restrict__ xq) {
    int t = blockIdx.x * blockDim.x + threadIdx.x;  // over Nc*16 uint2 granules
    if (t >= Nc * 16) return;
    int l4 = t & 3;
    int qn = t >> 2;            // q*Nc + n
    int q = qn / Nc;
    int n = qn - q * Nc;
    float4 v;
    if (n < Uc) v = reinterpret_cast<const float4*>(Gu)[n * 16 + q * 4 + l4];
    else        v = reinterpret_cast<const float4*>(Gi)[(n - Uc) * 16 + q * 4 + l4];
    H4 o;
    o.h[0] = (h16)v.x; o.h[1] = (h16)v.y; o.h[2] = (h16)v.z; o.h[3] = (h16)v.w;
    xq[t] = o.u;
}

// gather propagation for ONE quarter slice (32 B rows), 4 lanes/row, 4x ILP.
// x, xn already offset to quarter base; working set fits per-XCD L2.
__global__ void k_gprop_q(const int* __restrict__ rowptr, const int2* __restrict__ csr,
                          const uint2* __restrict__ x, uint2* __restrict__ xn) {
    int t = blockIdx.x * blockDim.x + threadIdx.x;
    int n = t >> 2, l = t & 3;
    if (n >= Nc) return;
    int e0 = rowptr[n], e1 = rowptr[n + 1];
    float acc[4] = {0.f, 0.f, 0.f, 0.f};
    int e = e0;
    for (; e + 4 <= e1; e += 4) {
        int2 s0 = csr[e], s1 = csr[e + 1], s2 = csr[e + 2], s3 = csr[e + 3];
        H4 v0, v1, v2, v3;
        v0.u = x[s0.x * 4 + l];
        v1.u = x[s1.x * 4 + l];
        v2.u = x[s2.x * 4 + l];
        v3.u = x[s3.x * 4 + l];
        float c0 = __int_as_float(s0.y), c1 = __int_as_float(s1.y);
        float c2 = __int_as_float(s2.y), c3 = __int_as_float(s3.y);
#pragma unroll
        for (int j = 0; j < 4; ++j)
            acc[j] += c0 * (float)v0.h[j] + c1 * (float)v1.h[j]
                    + c2 * (float)v2.h[j] + c3 * (float)v3.h[j];
    }
    for (; e < e1; ++e) {
        int2 sc = csr[e];
        float c = __int_as_float(sc.y);
        H4 v; v.u = x[sc.x * 4 + l];
#pragma unroll
        for (int j = 0; j < 4; ++j) acc[j] += c * (float)v.h[j];
    }
    H4 o;
#pragma unroll
    for (int j = 0; j < 4; ++j) o.h[j] = (h16)acc[j];
    xn[n * 4 + l] = o.u;
}

// fused batch-side: acc = x0 + a1 x1 + a2 x2 + a3 (A x2), then dot.
// 16 lanes per pair; lane l: quarter q=l>>2, granule l4=l&3, dims [4l,4l+4).
__global__ void k_final(const float* __restrict__ Gu, const float* __restrict__ Gi,
                        const uint2* __restrict__ x1, const uint2* __restrict__ x2,
                        const int* __restrict__ rowptr, const int2* __restrict__ csr,
                        const int* __restrict__ users, const int* __restrict__ items,
                        float* __restrict__ out) {
    int t = blockIdx.x * blockDim.x + threadIdx.x;
    int wid = t >> 4, l = t & 15;
    if (wid >= Bc) return;
    int qoff = (l >> 2) * Nc;   // quarter base (rows)
    int l4 = l & 3;

    float uv[4], iv[4];
#pragma unroll
    for (int side = 0; side < 2; ++side) {
        int n = side ? (Uc + items[wid]) : users[wid];
        float4 bv = side ? reinterpret_cast<const float4*>(Gi)[(n - Uc) * 16 + l]
                         : reinterpret_cast<const float4*>(Gu)[n * 16 + l];
        H4 h1, h2;
        h1.u = x1[(size_t)(qoff + n) * 4 + l4];
        h2.u = x2[(size_t)(qoff + n) * 4 + l4];
        float a[4];
        a[0] = bv.x + 0.5f * (float)h1.h[0] + (1.f / 3.f) * (float)h2.h[0];
        a[1] = bv.y + 0.5f * (float)h1.h[1] + (1.f / 3.f) * (float)h2.h[1];
        a[2] = bv.z + 0.5f * (float)h1.h[2] + (1.f / 3.f) * (float)h2.h[2];
        a[3] = bv.w + 0.5f * (float)h1.h[3] + (1.f / 3.f) * (float)h2.h[3];

        float su[4] = {0.f, 0.f, 0.f, 0.f};
        int e0 = rowptr[n], e1 = rowptr[n + 1];
        int e = e0;
        for (; e + 4 <= e1; e += 4) {
            int2 s0 = csr[e], s1 = csr[e + 1], s2 = csr[e + 2], s3 = csr[e + 3];
            H4 v0, v1, v2, v3;
            v0.u = x2[(size_t)(qoff + s0.x) * 4 + l4];
            v1.u = x2[(size_t)(qoff + s1.x) * 4 + l4];
            v2.u = x2[(size_t)(qoff + s2.x) * 4 + l4];
            v3.u = x2[(size_t)(qoff + s3.x) * 4 + l4];
            float c0 = __int_as_float(s0.y), c1 = __int_as_float(s1.y);
            float c2 = __int_as_float(s2.y), c3 = __int_as_float(s3.y);
#pragma unroll
            for (int j = 0; j < 4; ++j)
                su[j] += c0 * (float)v0.h[j] + c1 * (float)v1.h[j]
                       + c2 * (float)v2.h[j] + c3 * (float)v3.h[j];
        }
        for (; e < e1; ++e) {
            int2 sc = csr[e];
            float c = __int_as_float(sc.y);
            H4 v; v.u = x2[(size_t)(qoff + sc.x) * 4 + l4];
#pragma unroll
            for (int j = 0; j < 4; ++j) su[j] += c * (float)v.h[j];
        }
#pragma unroll
        for (int j = 0; j < 4; ++j) {
            float p = a[j] + 0.25f * su[j];
            if (side == 0) uv[j] = p; else iv[j] = p;
        }
    }

    float p = uv[0] * iv[0] + uv[1] * iv[1] + uv[2] * iv[2] + uv[3] * iv[3];
    p += __shfl_xor(p, 8, 16);
    p += __shfl_xor(p, 4, 16);
    p += __shfl_xor(p, 2, 16);
    p += __shfl_xor(p, 1, 16);
    if (l == 0) out[wid] = p;
}

// ---------------- launch ----------------

extern "C" void kernel_launch(void* const* d_in, const int* in_sizes, int n_in,
                              void* d_out, int out_size, void* d_ws, size_t ws_size,
                              hipStream_t stream) {
    const float* Gu = (const float*)d_in[0];
    const float* Gi = (const float*)d_in[1];
    const float* F  = (const float*)d_in[2];
    const float* pw = (const float*)d_in[3];
    const float* pb = (const float*)d_in[4];
    const float* ef = (const float*)d_in[5];
    const int*   ei = (const int*)d_in[6];   // [2, 2E]
    const int* users = (const int*)d_in[7];
    const int* items = (const int*)d_in[8];
    float* out = (float*)d_out;

    float* ws = (float*)d_ws;
    float*    Fp     = ws;                          // 64
    float*    dinv   = Fp + 64;                     // N
    unsigned* deg    = (unsigned*)(dinv + Nc);      // N
    int*      rowptr = (int*)(deg + Nc);            // N+16
    int*      cursor = rowptr + (Nc + 16);          // N
    int*      bsums  = cursor + Nc;                 // 256
    int2*     csr    = (int2*)(bsums + 256);        // 2E int2 (16 MB)
    h16*      xin    = (h16*)(csr + 2 * Ec);        // N*64 fp16 quarter-major
    h16*      xa     = xin + (size_t)Nc * 64;       // N*64 fp16 quarter-major
    h16*      xb     = xa + (size_t)Nc * 64;        // N*64 fp16 quarter-major

    const int* un  = ei;            // user ids (first half of row 0)
    const int* in_ = ei + 2 * Ec;   // item node ids >= U (first half of row 1)

    k_zero<<<(Nc / 4 + 255) / 256, 256, 0, stream>>>((uint4*)deg);
    k_deg2_fproj<<<(Ec + 255) / 256, 256, 0, stream>>>(un, in_, deg, F, pw, Fp);
    k_scan1<<<NBS, 256, 0, stream>>>(deg, rowptr, bsums, dinv);
    k_scan3<<<(Nc + 255) / 256, 256, 0, stream>>>(rowptr, bsums, cursor);
    k_build<<<(Ec * 16) / 256, 256, 0, stream>>>(un, in_, ef, Fp, pb, dinv, cursor, csr);
    k_xin<<<(Nc * 16 + 255) / 256, 256, 0, stream>>>(Gu, Gi, (uint2*)xin);

    const int gpb = (Nc * 4 + 255) / 256;
    for (int q = 0; q < 4; ++q)   // layer 1: xin -> xa, per quarter slice
        k_gprop_q<<<gpb, 256, 0, stream>>>(rowptr, csr,
            (const uint2*)xin + (size_t)q * Nc * 4, (uint2*)xa + (size_t)q * Nc * 4);
    for (int q = 0; q < 4; ++q)   // layer 2: xa -> xb
        k_gprop_q<<<gpb, 256, 0, stream>>>(rowptr, csr,
            (const uint2*)xa + (size_t)q * Nc * 4, (uint2*)xb + (size_t)q * Nc * 4);

    k_final<<<(Bc * 16 + 255) / 256, 256, 0, stream>>>(Gu, Gi, (const uint2*)xa, (const uint2*)xb,
                                                       rowptr, csr, users, items, out);
}

// Round 11
// 350.398 us; speedup vs baseline: 2.5628x; 1.2525x over previous
//
#include <hip/hip_runtime.h>

constexpr int Uc = 100000;
constexpr int Ic = 50000;
constexpr int Nc = 150000;   // U + I
constexpr int Ec = 1000000;
constexpr int Bc = 16384;
constexpr int NBS = (Nc + 1023) / 1024;  // scan chunks = 147

typedef _Float16 h16;
union H8 { uint4 u; h16 h[8]; };

// ---------------- kernels ----------------

__global__ void k_zero(uint4* __restrict__ deg4) {
    int i = blockIdx.x * blockDim.x + threadIdx.x;
    if (i < Nc / 4) deg4[i] = make_uint4(0u, 0u, 0u, 0u);
}

// deg count over undirected edges + (block 0) Fp[d] = F[d,:] @ pw
__global__ void k_deg2_fproj(const int* __restrict__ un, const int* __restrict__ in_,
                             unsigned* __restrict__ deg,
                             const float* __restrict__ F, const float* __restrict__ pw,
                             float* __restrict__ Fp) {
    if (blockIdx.x == 0 && threadIdx.x < 64) {
        int d = threadIdx.x;
        float s = 0.f;
#pragma unroll
        for (int j = 0; j < 64; ++j) s += F[d * 64 + j] * pw[j];
        Fp[d] = s;
    }
    int e = blockIdx.x * blockDim.x + threadIdx.x;
    if (e < Ec) {
        atomicAdd(&deg[un[e]], 1u);
        atomicAdd(&deg[in_[e]], 1u);
    }
}

// --- scan phase 1: per-1024-chunk exclusive scan of deg; also writes dinv ---
__global__ void k_scan1(const unsigned* __restrict__ deg, int* __restrict__ rowptr,
                        int* __restrict__ bsums, float* __restrict__ dinv) {
    __shared__ int sh[256];
    int tid = threadIdx.x, bid = blockIdx.x;
    int base = bid * 1024 + tid * 4;
    int v0 = (base + 0 < Nc) ? (int)deg[base + 0] : 0;
    int v1 = (base + 1 < Nc) ? (int)deg[base + 1] : 0;
    int v2 = (base + 2 < Nc) ? (int)deg[base + 2] : 0;
    int v3 = (base + 3 < Nc) ? (int)deg[base + 3] : 0;
    if (base + 0 < Nc) dinv[base + 0] = v0 ? rsqrtf((float)v0) : 0.f;
    if (base + 1 < Nc) dinv[base + 1] = v1 ? rsqrtf((float)v1) : 0.f;
    if (base + 2 < Nc) dinv[base + 2] = v2 ? rsqrtf((float)v2) : 0.f;
    if (base + 3 < Nc) dinv[base + 3] = v3 ? rsqrtf((float)v3) : 0.f;
    int s = v0 + v1 + v2 + v3;
    sh[tid] = s;
    __syncthreads();
    for (int off = 1; off < 256; off <<= 1) {
        int t = (tid >= off) ? sh[tid - off] : 0;
        __syncthreads();
        sh[tid] += t;
        __syncthreads();
    }
    int excl = sh[tid] - s;
    if (tid == 255) bsums[bid] = sh[255];
    if (base + 0 < Nc) rowptr[base + 0] = excl;
    if (base + 1 < Nc) rowptr[base + 1] = excl + v0;
    if (base + 2 < Nc) rowptr[base + 2] = excl + v0 + v1;
    if (base + 3 < Nc) rowptr[base + 3] = excl + v0 + v1 + v2;
}

// bsums scan folded in (each block redundantly scans the 147 sums in LDS)
__global__ void k_scan3(int* __restrict__ rowptr, const int* __restrict__ bsums,
                        int* __restrict__ cursor) {
    __shared__ int sh[256];
    int tid = threadIdx.x;
    int v = (tid < NBS) ? bsums[tid] : 0;
    sh[tid] = v;
    __syncthreads();
    for (int off = 1; off < 256; off <<= 1) {
        int t = (tid >= off) ? sh[tid - off] : 0;
        __syncthreads();
        sh[tid] += t;
        __syncthreads();
    }
    int excl = sh[tid] - v;
    __syncthreads();
    sh[tid] = excl;
    __syncthreads();
    int i = blockIdx.x * blockDim.x + threadIdx.x;
    if (i < Nc) {
        int r = rowptr[i] + sh[i >> 10];
        rowptr[i] = r;
        cursor[i] = r;
    }
    if (i == 0) rowptr[Nc] = 2 * Ec;
}

// fused: edge-weight projection + CSR scatter (both directions, same coef)
__global__ void k_build(const int* __restrict__ un, const int* __restrict__ in_,
                        const float* __restrict__ ef, const float* __restrict__ Fp,
                        const float* __restrict__ pb, const float* __restrict__ dinv,
                        int* __restrict__ cursor, int2* __restrict__ csr) {
    int t = blockIdx.x * blockDim.x + threadIdx.x;
    int e = t >> 4, l = t & 15;
    if (e >= Ec) return;
    float4 f = reinterpret_cast<const float4*>(ef)[(size_t)e * 16 + l];
    float4 w = reinterpret_cast<const float4*>(Fp)[l];
    float s = f.x * w.x + f.y * w.y + f.z * w.z + f.w * w.w;
    s += __shfl_xor(s, 8, 16);
    s += __shfl_xor(s, 4, 16);
    s += __shfl_xor(s, 2, 16);
    s += __shfl_xor(s, 1, 16);
    if (l == 0 || l == 8) {
        int uu = un[e], ii = in_[e];
        float c = dinv[uu] * dinv[ii] * (s + pb[0]);
        if (l == 0) {
            int pos = atomicAdd(&cursor[ii], 1);
            csr[pos] = make_int2(uu, __float_as_int(c));
        } else {
            int pos = atomicAdd(&cursor[uu], 1);
            csr[pos] = make_int2(ii, __float_as_int(c));
        }
    }
}

// convert concat(Gu,Gi) f32 -> xin fp16 (8 fp16 per thread = uint4), row-major
__global__ void k_xin(const float* __restrict__ Gu, const float* __restrict__ Gi,
                      uint4* __restrict__ xin) {
    int t = blockIdx.x * blockDim.x + threadIdx.x;  // over Nc*8 octets
    if (t >= Nc * 8) return;
    const float4* g;
    int idx;
    if (t < Uc * 8) { g = reinterpret_cast<const float4*>(Gu); idx = t * 2; }
    else            { g = reinterpret_cast<const float4*>(Gi); idx = (t - Uc * 8) * 2; }
    float4 a = g[idx], b = g[idx + 1];
    H8 o;
    o.h[0] = (h16)a.x; o.h[1] = (h16)a.y; o.h[2] = (h16)a.z; o.h[3] = (h16)a.w;
    o.h[4] = (h16)b.x; o.h[5] = (h16)b.y; o.h[6] = (h16)b.z; o.h[7] = (h16)b.w;
    xin[t] = o.u;
}

// gather propagation: fp16 rows, 8 lanes x uint4 per row, 4x ILP, single launch.
__global__ void k_gprop(const int* __restrict__ rowptr, const int2* __restrict__ csr,
                        const uint4* __restrict__ x, uint4* __restrict__ xn) {
    int t = blockIdx.x * blockDim.x + threadIdx.x;
    int n = t >> 3, l = t & 7;
    if (n >= Nc) return;
    int e0 = rowptr[n], e1 = rowptr[n + 1];
    float acc[8] = {0.f, 0.f, 0.f, 0.f, 0.f, 0.f, 0.f, 0.f};
    int e = e0;
    for (; e + 4 <= e1; e += 4) {
        int2 s0 = csr[e], s1 = csr[e + 1], s2 = csr[e + 2], s3 = csr[e + 3];
        H8 v0, v1, v2, v3;
        v0.u = x[s0.x * 8 + l];
        v1.u = x[s1.x * 8 + l];
        v2.u = x[s2.x * 8 + l];
        v3.u = x[s3.x * 8 + l];
        float c0 = __int_as_float(s0.y), c1 = __int_as_float(s1.y);
        float c2 = __int_as_float(s2.y), c3 = __int_as_float(s3.y);
#pragma unroll
        for (int j = 0; j < 8; ++j)
            acc[j] += c0 * (float)v0.h[j] + c1 * (float)v1.h[j]
                    + c2 * (float)v2.h[j] + c3 * (float)v3.h[j];
    }
    for (; e < e1; ++e) {
        int2 sc = csr[e];
        float c = __int_as_float(sc.y);
        H8 v; v.u = x[sc.x * 8 + l];
#pragma unroll
        for (int j = 0; j < 8; ++j) acc[j] += c * (float)v.h[j];
    }
    H8 o;
#pragma unroll
    for (int j = 0; j < 8; ++j) o.h[j] = (h16)acc[j];
    xn[n * 8 + l] = o.u;
}

// fused batch-side: acc = x0 + a1 x1 + a2 x2 + a3 (A x2), then dot.
// 8 lanes per (user,item) pair; lane j covers dims [8j, 8j+8).
__global__ void k_final(const float* __restrict__ Gu, const float* __restrict__ Gi,
                        const uint4* __restrict__ x1, const uint4* __restrict__ x2,
                        const int* __restrict__ rowptr, const int2* __restrict__ csr,
                        const int* __restrict__ users, const int* __restrict__ items,
                        float* __restrict__ out) {
    int t = blockIdx.x * blockDim.x + threadIdx.x;
    int wid = t >> 3, j8 = t & 7;
    if (wid >= Bc) return;
    int un = users[wid];
    int in_ = Uc + items[wid];

    float a2[2][8];
#pragma unroll
    for (int side = 0; side < 2; ++side) {
        int n = side ? in_ : un;
        const float4* g = side ? reinterpret_cast<const float4*>(Gi)
                               : reinterpret_cast<const float4*>(Gu);
        int gi = (side ? (n - Uc) : n) * 16 + 2 * j8;
        float4 ba = g[gi], bb = g[gi + 1];
        H8 h1, h2;
        h1.u = x1[(size_t)n * 8 + j8];
        h2.u = x2[(size_t)n * 8 + j8];
        float a[8];
        a[0] = ba.x; a[1] = ba.y; a[2] = ba.z; a[3] = ba.w;
        a[4] = bb.x; a[5] = bb.y; a[6] = bb.z; a[7] = bb.w;
#pragma unroll
        for (int j = 0; j < 8; ++j)
            a[j] += 0.5f * (float)h1.h[j] + (1.f / 3.f) * (float)h2.h[j];

        float su[8] = {0.f, 0.f, 0.f, 0.f, 0.f, 0.f, 0.f, 0.f};
        int e0 = rowptr[n], e1 = rowptr[n + 1];
        int e = e0;
        for (; e + 4 <= e1; e += 4) {
            int2 s0 = csr[e], s1 = csr[e + 1], s2 = csr[e + 2], s3 = csr[e + 3];
            H8 v0, v1, v2, v3;
            v0.u = x2[(size_t)s0.x * 8 + j8];
            v1.u = x2[(size_t)s1.x * 8 + j8];
            v2.u = x2[(size_t)s2.x * 8 + j8];
            v3.u = x2[(size_t)s3.x * 8 + j8];
            float c0 = __int_as_float(s0.y), c1 = __int_as_float(s1.y);
            float c2 = __int_as_float(s2.y), c3 = __int_as_float(s3.y);
#pragma unroll
            for (int j = 0; j < 8; ++j)
                su[j] += c0 * (float)v0.h[j] + c1 * (float)v1.h[j]
                       + c2 * (float)v2.h[j] + c3 * (float)v3.h[j];
        }
        for (; e < e1; ++e) {
            int2 sc = csr[e];
            float c = __int_as_float(sc.y);
            H8 v; v.u = x2[(size_t)sc.x * 8 + j8];
#pragma unroll
            for (int j = 0; j < 8; ++j) su[j] += c * (float)v.h[j];
        }
#pragma unroll
        for (int j = 0; j < 8; ++j) a2[side][j] = a[j] + 0.25f * su[j];
    }

    float p = 0.f;
#pragma unroll
    for (int j = 0; j < 8; ++j) p += a2[0][j] * a2[1][j];
    p += __shfl_xor(p, 4, 8);
    p += __shfl_xor(p, 2, 8);
    p += __shfl_xor(p, 1, 8);
    if (j8 == 0) out[wid] = p;
}

// ---------------- launch ----------------

extern "C" void kernel_launch(void* const* d_in, const int* in_sizes, int n_in,
                              void* d_out, int out_size, void* d_ws, size_t ws_size,
                              hipStream_t stream) {
    const float* Gu = (const float*)d_in[0];
    const float* Gi = (const float*)d_in[1];
    const float* F  = (const float*)d_in[2];
    const float* pw = (const float*)d_in[3];
    const float* pb = (const float*)d_in[4];
    const float* ef = (const float*)d_in[5];
    const int*   ei = (const int*)d_in[6];   // [2, 2E]
    const int* users = (const int*)d_in[7];
    const int* items = (const int*)d_in[8];
    float* out = (float*)d_out;

    float* ws = (float*)d_ws;
    float*    Fp     = ws;                          // 64
    float*    dinv   = Fp + 64;                     // N
    unsigned* deg    = (unsigned*)(dinv + Nc);      // N
    int*      rowptr = (int*)(deg + Nc);            // N+16
    int*      cursor = rowptr + (Nc + 16);          // N
    int*      bsums  = cursor + Nc;                 // 256
    int2*     csr    = (int2*)(bsums + 256);        // 2E int2 (16 MB)
    h16*      xin    = (h16*)(csr + 2 * Ec);        // N*64 fp16 row-major
    h16*      xa     = xin + (size_t)Nc * 64;       // N*64 fp16
    h16*      xb     = xa + (size_t)Nc * 64;        // N*64 fp16

    const int* un  = ei;            // user ids (first half of row 0)
    const int* in_ = ei + 2 * Ec;   // item node ids >= U (first half of row 1)

    k_zero<<<(Nc / 4 + 255) / 256, 256, 0, stream>>>((uint4*)deg);
    k_deg2_fproj<<<(Ec + 255) / 256, 256, 0, stream>>>(un, in_, deg, F, pw, Fp);
    k_scan1<<<NBS, 256, 0, stream>>>(deg, rowptr, bsums, dinv);
    k_scan3<<<(Nc + 255) / 256, 256, 0, stream>>>(rowptr, bsums, cursor);
    k_build<<<(Ec * 16) / 256, 256, 0, stream>>>(un, in_, ef, Fp, pb, dinv, cursor, csr);
    k_xin<<<(Nc * 8 + 255) / 256, 256, 0, stream>>>(Gu, Gi, (uint4*)xin);

    // layer 1: xin -> xa ; layer 2: xa -> xb  (single launch each, full range)
    k_gprop<<<(Nc * 8 + 255) / 256, 256, 0, stream>>>(rowptr, csr, (const uint4*)xin, (uint4*)xa);
    k_gprop<<<(Nc * 8 + 255) / 256, 256, 0, stream>>>(rowptr, csr, (const uint4*)xa, (uint4*)xb);

    // fused: alpha-weighted batch accumulation + layer-3 on the fly + dot
    k_final<<<(Bc * 8 + 255) / 256, 256, 0, stream>>>(Gu, Gi, (const uint4*)xa, (const uint4*)xb,
                                                      rowptr, csr, users, items, out);
}